// Round 5
// baseline (353.816 us; speedup 1.0000x reference)
//
#include <hip/hip_runtime.h>
#include <math.h>

#define B_ 4
#define T_ 1024
#define D_ 2048
#define NH 16
#define NKV 4
#define HD 128
#define KV_D 512    // NKV * HD
#define QKV_W 3072  // D_ + 2*KV_D : fused projection width

typedef __attribute__((ext_vector_type(8))) short short8;   // 8 x bf16 (4 VGPRs)
typedef __attribute__((ext_vector_type(4))) float f32x4;    // MFMA accumulator

// fp32 -> bf16 round-to-nearest-even (finite inputs)
__device__ __forceinline__ ushort f2b(float f) {
    unsigned u = __float_as_uint(f);
    return (ushort)((u + 0x7fffu + ((u >> 16) & 1u)) >> 16);
}
__device__ __forceinline__ float b2f(ushort u) {
    return __uint_as_float((unsigned)u << 16);
}

#define ASYNC_COPY16(g, l)                                                  \
    __builtin_amdgcn_global_load_lds(                                       \
        (const __attribute__((address_space(1))) void*)(g),                 \
        (__attribute__((address_space(3))) void*)(l), 16, 0, 0)

// ---------------------------------------------------------------------------
// prep_all: one dispatch for all input prep (5 independent jobs by bid range):
//   [0,8192)       cast x fp32 -> bf16 (4 elem/thread)
//   [8192,12288)   Wq  -> WqkvT rows 0..2047      (transpose+cast)
//   [12288,13312)  Wk  -> WqkvT rows 2048..2559
//   [13312,14336)  Wv  -> WqkvT rows 2560..3071
//   [14336,18432)  Wo  -> WoT
// ---------------------------------------------------------------------------
__global__ __launch_bounds__(256) void prep_all(const float* __restrict__ x,
                                                const float* __restrict__ Wq,
                                                const float* __restrict__ Wk,
                                                const float* __restrict__ Wv,
                                                const float* __restrict__ Wo,
                                                ushort* __restrict__ xb,
                                                ushort* __restrict__ WqkvT,
                                                ushort* __restrict__ WoT) {
    __shared__ float tile[32][33];
    const int bid = blockIdx.x;
    if (bid < 8192) {                      // cast job
        const int i = bid * 256 + threadIdx.x;
        const float4 v = ((const float4*)x)[i];
        ushort4 u;
        u.x = f2b(v.x); u.y = f2b(v.y); u.z = f2b(v.z); u.w = f2b(v.w);
        ((ushort4*)xb)[i] = u;
        return;
    }
    // transpose jobs: W [2048][N] fp32 -> WT [N][2048] bf16
    const float* W;
    ushort* WT;
    int N, rb;
    if (bid < 12288)      { W = Wq; WT = WqkvT;                           N = D_;   rb = bid - 8192; }
    else if (bid < 13312) { W = Wk; WT = WqkvT + (size_t)D_ * D_;         N = KV_D; rb = bid - 12288; }
    else if (bid < 14336) { W = Wv; WT = WqkvT + (size_t)(D_+KV_D) * D_;  N = KV_D; rb = bid - 13312; }
    else                  { W = Wo; WT = WoT;                             N = D_;   rb = bid - 14336; }
    const int bxn = N / 32;
    const int n0 = (rb % bxn) * 32, k0 = (rb / bxn) * 32;
    const int tx = threadIdx.x & 31, ty = threadIdx.x >> 5;  // 32 x 8
    for (int i = ty; i < 32; i += 8)
        tile[i][tx] = W[(size_t)(k0 + i) * N + n0 + tx];
    __syncthreads();
    for (int i = ty; i < 32; i += 8)
        WT[(size_t)(n0 + i) * D_ + k0 + tx] = f2b(tile[tx][i]);
}

// ---------------------------------------------------------------------------
// m97-style bf16 MFMA GEMM: C[M,N] = A[M,K] bf16 x BT[N,K] bf16.
// 128x128 tile, BK=32, 4 waves, global_load_lds width-16.
// OUT_BF16 selects fp32 or bf16 C. (verified rounds 2-4)
// ---------------------------------------------------------------------------
template <bool OUT_BF16>
__global__ __launch_bounds__(256) void gemm_bf16_t(const ushort* __restrict__ A,
                                                   const ushort* __restrict__ BT,
                                                   void* __restrict__ Cv,
                                                   int M, int N, int K) {
    __shared__ ushort As[128 * 32];
    __shared__ ushort Bs[128 * 32];
    const int tid = threadIdx.x;
    const int m0 = blockIdx.y * 128, n0 = blockIdx.x * 128;
    const int wave = tid >> 6, lane = tid & 63;
    const int wm = (wave >> 1) * 64, wn = (wave & 1) * 64;
    const int lrow = lane & 15;
    const int quad = lane >> 4;

    f32x4 acc[4][4];
    const f32x4 zero = {0.f, 0.f, 0.f, 0.f};
#pragma unroll
    for (int i = 0; i < 4; ++i)
#pragma unroll
        for (int j = 0; j < 4; ++j) acc[i][j] = zero;

    const int srow = tid >> 2;
    const int scol = (tid & 3) * 8;
    const ushort* Ag = A + (size_t)(m0 + srow) * K + scol;
    const ushort* Bg = BT + (size_t)(n0 + srow) * K + scol;
    ushort* AsT = As + tid * 8;
    ushort* BsT = Bs + tid * 8;

    for (int k0 = 0; k0 < K; k0 += 32) {
        ASYNC_COPY16(Ag + k0, AsT);
        ASYNC_COPY16(Ag + k0 + (size_t)64 * K, AsT + 64 * 32);
        ASYNC_COPY16(Bg + k0, BsT);
        ASYNC_COPY16(Bg + k0 + (size_t)64 * K, BsT + 64 * 32);
        __syncthreads();

        short8 a[4], b[4];
#pragma unroll
        for (int mt = 0; mt < 4; ++mt)
            a[mt] = *(const short8*)&As[(wm + mt * 16 + lrow) * 32 + quad * 8];
#pragma unroll
        for (int nt = 0; nt < 4; ++nt)
            b[nt] = *(const short8*)&Bs[(wn + nt * 16 + lrow) * 32 + quad * 8];
#pragma unroll
        for (int mt = 0; mt < 4; ++mt)
#pragma unroll
            for (int nt = 0; nt < 4; ++nt)
                acc[mt][nt] = __builtin_amdgcn_mfma_f32_16x16x32_bf16(
                    a[mt], b[nt], acc[mt][nt], 0, 0, 0);
        __syncthreads();
    }

    // C/D layout (verified m89): col = lane&15, row = (lane>>4)*4 + reg
    const int crow = quad * 4;
    const int ccol = lrow;
#pragma unroll
    for (int mt = 0; mt < 4; ++mt)
#pragma unroll
        for (int nt = 0; nt < 4; ++nt)
#pragma unroll
            for (int r = 0; r < 4; ++r) {
                const size_t idx = (size_t)(m0 + wm + mt * 16 + crow + r) * N +
                                   n0 + wn + nt * 16 + ccol;
                if (OUT_BF16) ((ushort*)Cv)[idx] = f2b(acc[mt][nt][r]);
                else          ((float*)Cv)[idx] = acc[mt][nt][r];
            }
}

// ---------------------------------------------------------------------------
// prep2: one dispatch for two independent jobs on the QKV buffer:
//   [0,20480)      RoPE in-place on Q (w/ 1/sqrt(HD) fold) and K columns
//   [20480,22528)  V columns -> Vt [B][NKV][HD][T] (d-major for PV MFMA)
// Jobs touch disjoint columns of QKV -> no ordering needed.
// ---------------------------------------------------------------------------
__global__ __launch_bounds__(256) void prep2(ushort* __restrict__ QKV,
                                             ushort* __restrict__ Vt) {
    __shared__ ushort tile[32][34];
    const int bid = blockIdx.x;
    if (bid < 20480) {                     // rope
        const int idx = bid * 256 + threadIdx.x;
        const int i = idx & 63;
        const int tmp = idx >> 6;
        const int head = tmp % (NH + NKV);
        const int bt = tmp / (NH + NKV);
        const int t = bt & (T_ - 1);
        // 10000^(-2i/128) = exp2(-i/64 * log2(10000))
        const float inv = exp2f((float)i * (-13.287712379549449f / 64.0f));
        const float ang = (float)t * inv;
        const float c = cosf(ang), s = sinf(ang);
        const bool isQ = head < NH;        // wave-uniform (64 idx share head)
        const size_t base = (size_t)bt * QKV_W +
                            (isQ ? head * HD : D_ + (head - NH) * HD);
        const float sc = isQ ? 0.08838834764831845f : 1.0f;
        const float x1 = b2f(QKV[base + i]);
        const float x2 = b2f(QKV[base + i + 64]);
        QKV[base + i]      = f2b((x1 * c - x2 * s) * sc);
        QKV[base + i + 64] = f2b((x2 * c + x1 * s) * sc);
        return;
    }
    // transpose_v
    const int b2 = bid - 20480;
    const int bkv = b2 >> 7;               // 128 blocks per (b,kv)
    const int rem = b2 & 127;
    const int t0 = (rem >> 2) * 32, d0 = (rem & 3) * 32;
    const int b = bkv >> 2, kv = bkv & 3;
    const int tx = threadIdx.x & 31, ty = threadIdx.x >> 5;  // 32 x 8
    for (int i = ty; i < 32; i += 8)
        tile[i][tx] = QKV[(size_t)(b * T_ + t0 + i) * QKV_W + D_ + KV_D + kv * HD + d0 + tx];
    __syncthreads();
    for (int i = ty; i < 32; i += 8)
        Vt[((size_t)((b * NKV + kv) * HD + d0 + i)) * T_ + t0 + tx] = tile[tx][i];
}

// ---------------------------------------------------------------------------
// MFMA flash attention v2: WG = 256 thr (4 waves); WG covers 128 q-rows,
// each wave 32 rows as TWO 16-row fragments (rb). K-loop over 64-wide
// s-tiles: per iter each wave does 64 MFMAs (2x the round-3 version) between
// the same two barriers, and each staged K/V tile now serves 128 q-rows.
// Waves fully below the diagonal skip compute (wave-uniform). Grid (64,8)
// with zigzag qt map so co-resident WG pairs have equal causal work.
// LDS = 54.3 KB -> 2 WG/CU.
// ---------------------------------------------------------------------------
__global__ __launch_bounds__(256) void attn_mfma(const ushort* __restrict__ QKV,
                                                 const ushort* __restrict__ Vt,
                                                 ushort* __restrict__ Yb) {
    __shared__ ushort Ks[64][136];       // [s][d]
    __shared__ ushort Vs[128][72];       // [d][s]
    __shared__ ushort Ps[4][2][16][72];  // per-wave, per-row-block P tile

    const int bh = blockIdx.x;
    const int yb2 = blockIdx.y;
    const int qt = (yb2 < 4) ? yb2 : 11 - yb2;   // zigzag: pairs sum to const
    const int b = bh >> 4, h = bh & 15;
    const int kvh = h >> 2;
    const int q0 = qt * 128;
    const int tid = threadIdx.x;
    const int wave = tid >> 6, lane = tid & 63;
    const int ln = lane & 15, quad = lane >> 4;

    // Q fragments (A-layout: m=ln, k=quad*8+j) for both row blocks
    short8 qf[2][4];
#pragma unroll
    for (int rb = 0; rb < 2; ++rb) {
        const ushort* qp = QKV + ((size_t)(b * T_ + q0 + wave * 32 + rb * 16 + ln)) * QKV_W + h * HD + quad * 8;
#pragma unroll
        for (int f = 0; f < 4; ++f) qf[rb][f] = *(const short8*)(qp + f * 32);
    }

    f32x4 acc[2][8];
    const f32x4 zero = {0.f, 0.f, 0.f, 0.f};
#pragma unroll
    for (int rb = 0; rb < 2; ++rb)
#pragma unroll
        for (int j = 0; j < 8; ++j) acc[rb][j] = zero;
    float m_r[2][4], l_r[2][4];
#pragma unroll
    for (int rb = 0; rb < 2; ++rb)
#pragma unroll
        for (int r = 0; r < 4; ++r) { m_r[rb][r] = -INFINITY; l_r[rb][r] = 0.f; }

    const int rowmax = q0 + wave * 32 + 31;   // last q-row this wave owns
    const int nk = 2 * qt + 2;                // 64-wide s-tiles needed

    for (int kt = 0; kt < nk; ++kt) {
        const int s0 = kt * 64;
        __syncthreads();   // protect previous-iteration Ks/Vs reads
        // stage K tile [64][128] from QKV cols D_ + kvh*HD (coalesced b128)
#pragma unroll
        for (int c = 0; c < 4; ++c) {
            const int cid = tid + 256 * c;
            const int s = cid >> 4, ch = cid & 15;
            *(short8*)&Ks[s][ch * 8] =
                *(const short8*)&QKV[((size_t)(b * T_ + s0 + s)) * QKV_W + D_ + kvh * HD + ch * 8];
        }
        // stage V^T tile [128][64]
#pragma unroll
        for (int c = 0; c < 4; ++c) {
            const int cid = tid + 256 * c;
            const int d = cid >> 3, ch = cid & 7;
            *(short8*)&Vs[d][ch * 8] =
                *(const short8*)&Vt[((size_t)((b * NKV + kvh) * HD + d)) * T_ + s0 + ch * 8];
        }
        __syncthreads();

        if (s0 > rowmax) continue;   // wave fully above-masked: staging only

#pragma unroll
        for (int rb = 0; rb < 2; ++rb) {
            // S = Q K^T : 4 col-tiles of 16
            float sc[4][4];
#pragma unroll
            for (int ct = 0; ct < 4; ++ct) {
                f32x4 s4 = zero;
#pragma unroll
                for (int f = 0; f < 4; ++f)
                    s4 = __builtin_amdgcn_mfma_f32_16x16x32_bf16(
                        qf[rb][f], *(const short8*)&Ks[ct * 16 + ln][f * 32 + quad * 8], s4, 0, 0, 0);
#pragma unroll
                for (int r = 0; r < 4; ++r) sc[ct][r] = s4[r];
            }
            // causal mask on the two diagonal-straddling iterations
            const int qrow = q0 + wave * 32 + rb * 16 + quad * 4;
            if (kt >= 2 * qt) {
#pragma unroll
                for (int ct = 0; ct < 4; ++ct)
#pragma unroll
                    for (int r = 0; r < 4; ++r)
                        if (s0 + ct * 16 + ln > qrow + r) sc[ct][r] = -INFINITY;
            }
            // online softmax per C-layout row (stats across 16-lane group)
            float alpha[4];
#pragma unroll
            for (int r = 0; r < 4; ++r) {
                float mx = fmaxf(fmaxf(sc[0][r], sc[1][r]), fmaxf(sc[2][r], sc[3][r]));
                mx = fmaxf(mx, __shfl_xor(mx, 1));
                mx = fmaxf(mx, __shfl_xor(mx, 2));
                mx = fmaxf(mx, __shfl_xor(mx, 4));
                mx = fmaxf(mx, __shfl_xor(mx, 8));
                const float mnew = fmaxf(m_r[rb][r], mx);
                alpha[r] = __expf(m_r[rb][r] - mnew);
                m_r[rb][r] = mnew;
#pragma unroll
                for (int ct = 0; ct < 4; ++ct) sc[ct][r] = __expf(sc[ct][r] - mnew);
                float sum = (sc[0][r] + sc[1][r]) + (sc[2][r] + sc[3][r]);
                sum += __shfl_xor(sum, 1);
                sum += __shfl_xor(sum, 2);
                sum += __shfl_xor(sum, 4);
                sum += __shfl_xor(sum, 8);
                l_r[rb][r] = l_r[rb][r] * alpha[r] + sum;
            }
            // P (C-layout) -> per-wave LDS (wave-private, no barrier needed)
#pragma unroll
            for (int ct = 0; ct < 4; ++ct)
#pragma unroll
                for (int r = 0; r < 4; ++r)
                    Ps[wave][rb][quad * 4 + r][ct * 16 + ln] = f2b(sc[ct][r]);
            // rescale O
#pragma unroll
            for (int j = 0; j < 8; ++j)
#pragma unroll
                for (int r = 0; r < 4; ++r) acc[rb][j][r] *= alpha[r];
            // P as A-fragments, two 32-wide k slices
            const short8 pa0 = *(const short8*)&Ps[wave][rb][ln][quad * 8];
            const short8 pa1 = *(const short8*)&Ps[wave][rb][ln][32 + quad * 8];
#pragma unroll
            for (int j = 0; j < 8; ++j) {
                acc[rb][j] = __builtin_amdgcn_mfma_f32_16x16x32_bf16(
                    pa0, *(const short8*)&Vs[j * 16 + ln][quad * 8], acc[rb][j], 0, 0, 0);
                acc[rb][j] = __builtin_amdgcn_mfma_f32_16x16x32_bf16(
                    pa1, *(const short8*)&Vs[j * 16 + ln][32 + quad * 8], acc[rb][j], 0, 0, 0);
            }
        }
    }

#pragma unroll
    for (int rb = 0; rb < 2; ++rb) {
        float invl[4];
#pragma unroll
        for (int r = 0; r < 4; ++r) invl[r] = 1.f / l_r[rb][r];
        ushort* yp = Yb + ((size_t)(b * T_ + q0 + wave * 32 + rb * 16 + quad * 4)) * D_ + h * HD + ln;
#pragma unroll
        for (int r = 0; r < 4; ++r)
#pragma unroll
            for (int j = 0; j < 8; ++j)
                yp[(size_t)r * D_ + j * 16] = f2b(acc[rb][j][r] * invl[r]);
    }
}

// ---------------------------------------------------------------------------
extern "C" void kernel_launch(void* const* d_in, const int* in_sizes, int n_in,
                              void* d_out, int out_size, void* d_ws, size_t ws_size,
                              hipStream_t stream) {
    const float* x  = (const float*)d_in[0];
    const float* Wq = (const float*)d_in[1];
    const float* Wk = (const float*)d_in[2];
    const float* Wv = (const float*)d_in[3];
    const float* Wo = (const float*)d_in[4];
    float* out = (float*)d_out;

    // Workspace: 83,886,080 B exactly (== round-1 footprint, known to fit)
    char* w = (char*)d_ws;
    ushort* xb    = (ushort*)w;  w += (size_t)4096 * D_ * 2;      // 16.78 MB
    ushort* WqkvT = (ushort*)w;  w += (size_t)QKV_W * D_ * 2;     // 12.58 MB
    ushort* QKV   = (ushort*)w;  w += (size_t)4096 * QKV_W * 2;   // 25.17 MB
    ushort* Vt    = (ushort*)w;  w += (size_t)B_ * KV_D * T_ * 2; //  4.19 MB
    ushort* Yb    = (ushort*)w;  w += (size_t)4096 * D_ * 2;      // 16.78 MB
    ushort* WoT   = (ushort*)w;  w += (size_t)D_ * D_ * 2;        //  8.39 MB

    const int M = B_ * T_;  // 4096
    dim3 blk(256);

    // all input prep in one dispatch
    prep_all<<<18432, blk, 0, stream>>>(x, Wq, Wk, Wv, Wo, xb, WqkvT, WoT);

    // fused QKV projection: bf16 out, 768 WGs (3/CU)
    gemm_bf16_t<true><<<dim3(QKV_W / 128, M / 128), blk, 0, stream>>>(
        xb, WqkvT, QKV, M, QKV_W, D_);

    // rope (in-place Q/K) + V transpose in one dispatch
    prep2<<<22528, blk, 0, stream>>>(QKV, Vt);

    attn_mfma<<<dim3(B_ * NH, T_ / 128), blk, 0, stream>>>(QKV, Vt, Yb);

    // output projection: bf16 Y x bf16 Wo^T -> fp32 out
    gemm_bf16_t<false><<<dim3(D_ / 128, M / 128), blk, 0, stream>>>(
        Yb, WoT, out, M, D_, D_);
}

// Round 6
// 312.803 us; speedup vs baseline: 1.1311x; 1.1311x over previous
//
#include <hip/hip_runtime.h>
#include <math.h>

#define B_ 4
#define T_ 1024
#define D_ 2048
#define NH 16
#define NKV 4
#define HD 128
#define KV_D 512    // NKV * HD
#define QKV_W 3072  // D_ + 2*KV_D : fused projection width

typedef __attribute__((ext_vector_type(8))) short short8;   // 8 x bf16 (4 VGPRs)
typedef __attribute__((ext_vector_type(4))) float f32x4;    // MFMA accumulator

// fp32 -> bf16 round-to-nearest-even (finite inputs)
__device__ __forceinline__ ushort f2b(float f) {
    unsigned u = __float_as_uint(f);
    return (ushort)((u + 0x7fffu + ((u >> 16) & 1u)) >> 16);
}
__device__ __forceinline__ float b2f(ushort u) {
    return __uint_as_float((unsigned)u << 16);
}

// exp2 via v_exp_f32 (no hidden log2e multiply like __expf)
#if __has_builtin(__builtin_amdgcn_exp2f)
#define EXP2F(x) __builtin_amdgcn_exp2f(x)
#else
#define EXP2F(x) __expf((x) * 0.6931471805599453f)
#endif

#define ASYNC_COPY16(g, l)                                                  \
    __builtin_amdgcn_global_load_lds(                                       \
        (const __attribute__((address_space(1))) void*)(g),                 \
        (__attribute__((address_space(3))) void*)(l), 16, 0, 0)

// ---------------------------------------------------------------------------
// prep_all: one dispatch for all input prep (5 independent jobs by bid range):
//   [0,8192)       cast x fp32 -> bf16 (4 elem/thread)
//   [8192,12288)   Wq  -> WqkvT rows 0..2047      (transpose+cast)
//   [12288,13312)  Wk  -> WqkvT rows 2048..2559
//   [13312,14336)  Wv  -> WqkvT rows 2560..3071
//   [14336,18432)  Wo  -> WoT
// ---------------------------------------------------------------------------
__global__ __launch_bounds__(256) void prep_all(const float* __restrict__ x,
                                                const float* __restrict__ Wq,
                                                const float* __restrict__ Wk,
                                                const float* __restrict__ Wv,
                                                const float* __restrict__ Wo,
                                                ushort* __restrict__ xb,
                                                ushort* __restrict__ WqkvT,
                                                ushort* __restrict__ WoT) {
    __shared__ float tile[32][33];
    const int bid = blockIdx.x;
    if (bid < 8192) {                      // cast job
        const int i = bid * 256 + threadIdx.x;
        const float4 v = ((const float4*)x)[i];
        ushort4 u;
        u.x = f2b(v.x); u.y = f2b(v.y); u.z = f2b(v.z); u.w = f2b(v.w);
        ((ushort4*)xb)[i] = u;
        return;
    }
    // transpose jobs: W [2048][N] fp32 -> WT [N][2048] bf16
    const float* W;
    ushort* WT;
    int N, rb;
    if (bid < 12288)      { W = Wq; WT = WqkvT;                           N = D_;   rb = bid - 8192; }
    else if (bid < 13312) { W = Wk; WT = WqkvT + (size_t)D_ * D_;         N = KV_D; rb = bid - 12288; }
    else if (bid < 14336) { W = Wv; WT = WqkvT + (size_t)(D_+KV_D) * D_;  N = KV_D; rb = bid - 13312; }
    else                  { W = Wo; WT = WoT;                             N = D_;   rb = bid - 14336; }
    const int bxn = N / 32;
    const int n0 = (rb % bxn) * 32, k0 = (rb / bxn) * 32;
    const int tx = threadIdx.x & 31, ty = threadIdx.x >> 5;  // 32 x 8
    for (int i = ty; i < 32; i += 8)
        tile[i][tx] = W[(size_t)(k0 + i) * N + n0 + tx];
    __syncthreads();
    for (int i = ty; i < 32; i += 8)
        WT[(size_t)(n0 + i) * D_ + k0 + tx] = f2b(tile[tx][i]);
}

// ---------------------------------------------------------------------------
// m97-style bf16 MFMA GEMM: C[M,N] = A[M,K] bf16 x BT[N,K] bf16.
// 128x128 tile, BK=32, 4 waves, global_load_lds width-16.
// OUT_BF16 selects fp32 or bf16 C. (verified rounds 2-5)
// ---------------------------------------------------------------------------
template <bool OUT_BF16>
__global__ __launch_bounds__(256) void gemm_bf16_t(const ushort* __restrict__ A,
                                                   const ushort* __restrict__ BT,
                                                   void* __restrict__ Cv,
                                                   int M, int N, int K) {
    __shared__ ushort As[128 * 32];
    __shared__ ushort Bs[128 * 32];
    const int tid = threadIdx.x;
    const int m0 = blockIdx.y * 128, n0 = blockIdx.x * 128;
    const int wave = tid >> 6, lane = tid & 63;
    const int wm = (wave >> 1) * 64, wn = (wave & 1) * 64;
    const int lrow = lane & 15;
    const int quad = lane >> 4;

    f32x4 acc[4][4];
    const f32x4 zero = {0.f, 0.f, 0.f, 0.f};
#pragma unroll
    for (int i = 0; i < 4; ++i)
#pragma unroll
        for (int j = 0; j < 4; ++j) acc[i][j] = zero;

    const int srow = tid >> 2;
    const int scol = (tid & 3) * 8;
    const ushort* Ag = A + (size_t)(m0 + srow) * K + scol;
    const ushort* Bg = BT + (size_t)(n0 + srow) * K + scol;
    ushort* AsT = As + tid * 8;
    ushort* BsT = Bs + tid * 8;

    for (int k0 = 0; k0 < K; k0 += 32) {
        ASYNC_COPY16(Ag + k0, AsT);
        ASYNC_COPY16(Ag + k0 + (size_t)64 * K, AsT + 64 * 32);
        ASYNC_COPY16(Bg + k0, BsT);
        ASYNC_COPY16(Bg + k0 + (size_t)64 * K, BsT + 64 * 32);
        __syncthreads();

        short8 a[4], b[4];
#pragma unroll
        for (int mt = 0; mt < 4; ++mt)
            a[mt] = *(const short8*)&As[(wm + mt * 16 + lrow) * 32 + quad * 8];
#pragma unroll
        for (int nt = 0; nt < 4; ++nt)
            b[nt] = *(const short8*)&Bs[(wn + nt * 16 + lrow) * 32 + quad * 8];
#pragma unroll
        for (int mt = 0; mt < 4; ++mt)
#pragma unroll
            for (int nt = 0; nt < 4; ++nt)
                acc[mt][nt] = __builtin_amdgcn_mfma_f32_16x16x32_bf16(
                    a[mt], b[nt], acc[mt][nt], 0, 0, 0);
        __syncthreads();
    }

    // C/D layout (verified m89): col = lane&15, row = (lane>>4)*4 + reg
    const int crow = quad * 4;
    const int ccol = lrow;
#pragma unroll
    for (int mt = 0; mt < 4; ++mt)
#pragma unroll
        for (int nt = 0; nt < 4; ++nt)
#pragma unroll
            for (int r = 0; r < 4; ++r) {
                const size_t idx = (size_t)(m0 + wm + mt * 16 + crow + r) * N +
                                   n0 + wn + nt * 16 + ccol;
                if (OUT_BF16) ((ushort*)Cv)[idx] = f2b(acc[mt][nt][r]);
                else          ((float*)Cv)[idx] = acc[mt][nt][r];
            }
}

// ---------------------------------------------------------------------------
// prep2: one dispatch for two independent jobs on the QKV buffer:
//   [0,20480)      RoPE in-place on Q (folds (1/sqrt(HD))*log2(e)) and K cols
//   [20480,22528)  V columns -> Vt [B][NKV][HD][T] (d-major for PV MFMA)
// Jobs touch disjoint columns of QKV -> no ordering needed.
// ---------------------------------------------------------------------------
__global__ __launch_bounds__(256) void prep2(ushort* __restrict__ QKV,
                                             ushort* __restrict__ Vt) {
    __shared__ ushort tile[32][34];
    const int bid = blockIdx.x;
    if (bid < 20480) {                     // rope
        const int idx = bid * 256 + threadIdx.x;
        const int i = idx & 63;
        const int tmp = idx >> 6;
        const int head = tmp % (NH + NKV);
        const int bt = tmp / (NH + NKV);
        const int t = bt & (T_ - 1);
        // 10000^(-2i/128) = exp2(-i/64 * log2(10000))
        const float inv = exp2f((float)i * (-13.287712379549449f / 64.0f));
        const float ang = (float)t * inv;
        const float c = cosf(ang), s = sinf(ang);
        const bool isQ = head < NH;        // wave-uniform (64 idx share head)
        const size_t base = (size_t)bt * QKV_W +
                            (isQ ? head * HD : D_ + (head - NH) * HD);
        // Q scale: 1/sqrt(128) * log2(e) -> softmax runs in exp2 domain
        const float sc = isQ ? (0.08838834764831845f * 1.4426950408889634f) : 1.0f;
        const float x1 = b2f(QKV[base + i]);
        const float x2 = b2f(QKV[base + i + 64]);
        QKV[base + i]      = f2b((x1 * c - x2 * s) * sc);
        QKV[base + i + 64] = f2b((x2 * c + x1 * s) * sc);
        return;
    }
    // transpose_v
    const int b2 = bid - 20480;
    const int bkv = b2 >> 7;               // 128 blocks per (b,kv)
    const int rem = b2 & 127;
    const int t0 = (rem >> 2) * 32, d0 = (rem & 3) * 32;
    const int b = bkv >> 2, kv = bkv & 3;
    const int tx = threadIdx.x & 31, ty = threadIdx.x >> 5;  // 32 x 8
    for (int i = ty; i < 32; i += 8)
        tile[i][tx] = QKV[(size_t)(b * T_ + t0 + i) * QKV_W + D_ + KV_D + kv * HD + d0 + tx];
    __syncthreads();
    for (int i = ty; i < 32; i += 8)
        Vt[((size_t)((b * NKV + kv) * HD + d0 + i)) * T_ + t0 + tx] = tile[tx][i];
}

// ---------------------------------------------------------------------------
// MFMA flash attention (round-4 structure: 64 q-rows/WG, 3 WG/CU), plus:
//  - heavy-first dispatch: qt = 15 - blockIdx.y so diagonal (16-iter) WGs
//    launch first and light WGs backfill the tail
//  - exp2-domain softmax (log2e pre-folded into Q)
// WG = 256 thr (4 waves), LDS = 45056 B -> 3 WG/CU.
// ---------------------------------------------------------------------------
__global__ __launch_bounds__(256) void attn_mfma(const ushort* __restrict__ QKV,
                                                 const ushort* __restrict__ Vt,
                                                 ushort* __restrict__ Yb) {
    __shared__ ushort Ks[64][136];       // [s][d]
    __shared__ ushort Vs[128][72];       // [d][s]
    __shared__ ushort Ps[4][16][72];     // per-wave P tile [qrow][s]

    const int bh = blockIdx.x;
    const int qt = (int)gridDim.y - 1 - (int)blockIdx.y;  // heavy WGs first
    const int b = bh >> 4, h = bh & 15;
    const int kvh = h >> 2;
    const int q0 = qt * 64;
    const int tid = threadIdx.x;
    const int wave = tid >> 6, lane = tid & 63;
    const int ln = lane & 15, quad = lane >> 4;

    // Q fragments (A-layout: m=ln, k=quad*8+j), rows q0 + wave*16 + ln
    short8 qf[4];
    {
        const ushort* qp = QKV + ((size_t)(b * T_ + q0 + wave * 16 + ln)) * QKV_W + h * HD + quad * 8;
#pragma unroll
        for (int f = 0; f < 4; ++f) qf[f] = *(const short8*)(qp + f * 32);
    }

    f32x4 acc[8];
    const f32x4 zero = {0.f, 0.f, 0.f, 0.f};
#pragma unroll
    for (int j = 0; j < 8; ++j) acc[j] = zero;
    float m_r[4], l_r[4];
#pragma unroll
    for (int r = 0; r < 4; ++r) { m_r[r] = -INFINITY; l_r[r] = 0.f; }

    const int qrow = q0 + wave * 16 + quad * 4;   // C-layout row base (+r)

    for (int kt = 0; kt <= qt; ++kt) {
        const int s0 = kt * 64;
        __syncthreads();   // protect previous-iteration Ks/Vs reads
        // stage K tile [64][128] from QKV cols D_ + kvh*HD (coalesced b128)
#pragma unroll
        for (int c = 0; c < 4; ++c) {
            const int cid = tid + 256 * c;
            const int s = cid >> 4, ch = cid & 15;
            *(short8*)&Ks[s][ch * 8] =
                *(const short8*)&QKV[((size_t)(b * T_ + s0 + s)) * QKV_W + D_ + kvh * HD + ch * 8];
        }
        // stage V^T tile [128][64]
#pragma unroll
        for (int c = 0; c < 4; ++c) {
            const int cid = tid + 256 * c;
            const int d = cid >> 3, ch = cid & 7;
            *(short8*)&Vs[d][ch * 8] =
                *(const short8*)&Vt[((size_t)((b * NKV + kvh) * HD + d)) * T_ + s0 + ch * 8];
        }
        __syncthreads();

        // S = Q K^T : 4 col-tiles of 16
        float sc[4][4];
#pragma unroll
        for (int ct = 0; ct < 4; ++ct) {
            f32x4 s4 = zero;
#pragma unroll
            for (int f = 0; f < 4; ++f)
                s4 = __builtin_amdgcn_mfma_f32_16x16x32_bf16(
                    qf[f], *(const short8*)&Ks[ct * 16 + ln][f * 32 + quad * 8], s4, 0, 0, 0);
#pragma unroll
            for (int r = 0; r < 4; ++r) sc[ct][r] = s4[r];
        }
        // causal mask: only the diagonal tile needs it
        if (kt == qt) {
#pragma unroll
            for (int ct = 0; ct < 4; ++ct)
#pragma unroll
                for (int r = 0; r < 4; ++r)
                    if (s0 + ct * 16 + ln > qrow + r) sc[ct][r] = -INFINITY;
        }
        // online softmax per C-layout row, exp2 domain (log2e folded into Q)
        float alpha[4];
#pragma unroll
        for (int r = 0; r < 4; ++r) {
            float mx = fmaxf(fmaxf(sc[0][r], sc[1][r]), fmaxf(sc[2][r], sc[3][r]));
            mx = fmaxf(mx, __shfl_xor(mx, 1));
            mx = fmaxf(mx, __shfl_xor(mx, 2));
            mx = fmaxf(mx, __shfl_xor(mx, 4));
            mx = fmaxf(mx, __shfl_xor(mx, 8));
            const float mnew = fmaxf(m_r[r], mx);
            alpha[r] = EXP2F(m_r[r] - mnew);
            m_r[r] = mnew;
#pragma unroll
            for (int ct = 0; ct < 4; ++ct) sc[ct][r] = EXP2F(sc[ct][r] - mnew);
            float sum = (sc[0][r] + sc[1][r]) + (sc[2][r] + sc[3][r]);
            sum += __shfl_xor(sum, 1);
            sum += __shfl_xor(sum, 2);
            sum += __shfl_xor(sum, 4);
            sum += __shfl_xor(sum, 8);
            l_r[r] = l_r[r] * alpha[r] + sum;
        }
        // P (C-layout) -> per-wave LDS (wave-private, no barrier needed)
#pragma unroll
        for (int ct = 0; ct < 4; ++ct)
#pragma unroll
            for (int r = 0; r < 4; ++r)
                Ps[wave][quad * 4 + r][ct * 16 + ln] = f2b(sc[ct][r]);
        // rescale O
#pragma unroll
        for (int j = 0; j < 8; ++j)
#pragma unroll
            for (int r = 0; r < 4; ++r) acc[j][r] *= alpha[r];
        // P as A-fragments, two 32-wide k slices
        const short8 pa0 = *(const short8*)&Ps[wave][ln][quad * 8];
        const short8 pa1 = *(const short8*)&Ps[wave][ln][32 + quad * 8];
#pragma unroll
        for (int j = 0; j < 8; ++j) {
            acc[j] = __builtin_amdgcn_mfma_f32_16x16x32_bf16(
                pa0, *(const short8*)&Vs[j * 16 + ln][quad * 8], acc[j], 0, 0, 0);
            acc[j] = __builtin_amdgcn_mfma_f32_16x16x32_bf16(
                pa1, *(const short8*)&Vs[j * 16 + ln][32 + quad * 8], acc[j], 0, 0, 0);
        }
    }

    float invl[4];
#pragma unroll
    for (int r = 0; r < 4; ++r) invl[r] = 1.f / l_r[r];
    ushort* yb = Yb + ((size_t)(b * T_ + qrow)) * D_ + h * HD + ln;
#pragma unroll
    for (int r = 0; r < 4; ++r)
#pragma unroll
        for (int j = 0; j < 8; ++j)
            yb[(size_t)r * D_ + j * 16] = f2b(acc[j][r] * invl[r]);
}

// ---------------------------------------------------------------------------
extern "C" void kernel_launch(void* const* d_in, const int* in_sizes, int n_in,
                              void* d_out, int out_size, void* d_ws, size_t ws_size,
                              hipStream_t stream) {
    const float* x  = (const float*)d_in[0];
    const float* Wq = (const float*)d_in[1];
    const float* Wk = (const float*)d_in[2];
    const float* Wv = (const float*)d_in[3];
    const float* Wo = (const float*)d_in[4];
    float* out = (float*)d_out;

    // Workspace: 83,886,080 B exactly (== round-1 footprint, known to fit)
    char* w = (char*)d_ws;
    ushort* xb    = (ushort*)w;  w += (size_t)4096 * D_ * 2;      // 16.78 MB
    ushort* WqkvT = (ushort*)w;  w += (size_t)QKV_W * D_ * 2;     // 12.58 MB
    ushort* QKV   = (ushort*)w;  w += (size_t)4096 * QKV_W * 2;   // 25.17 MB
    ushort* Vt    = (ushort*)w;  w += (size_t)B_ * KV_D * T_ * 2; //  4.19 MB
    ushort* Yb    = (ushort*)w;  w += (size_t)4096 * D_ * 2;      // 16.78 MB
    ushort* WoT   = (ushort*)w;  w += (size_t)D_ * D_ * 2;        //  8.39 MB

    const int M = B_ * T_;  // 4096
    dim3 blk(256);

    // all input prep in one dispatch
    prep_all<<<18432, blk, 0, stream>>>(x, Wq, Wk, Wv, Wo, xb, WqkvT, WoT);

    // fused QKV projection: bf16 out, 768 WGs (3/CU)
    gemm_bf16_t<true><<<dim3(QKV_W / 128, M / 128), blk, 0, stream>>>(
        xb, WqkvT, QKV, M, QKV_W, D_);

    // rope (in-place Q/K, exp2-domain Q scale) + V transpose in one dispatch
    prep2<<<22528, blk, 0, stream>>>(QKV, Vt);

    attn_mfma<<<dim3(B_ * NH, T_ / 64), blk, 0, stream>>>(QKV, Vt, Yb);

    // output projection: bf16 Y x bf16 Wo^T -> fp32 out
    gemm_bf16_t<false><<<dim3(D_ / 128, M / 128), blk, 0, stream>>>(
        Yb, WoT, out, M, D_, D_);
}

// Round 7
// 297.708 us; speedup vs baseline: 1.1885x; 1.0507x over previous
//
#include <hip/hip_runtime.h>
#include <math.h>

#define B_ 4
#define T_ 1024
#define D_ 2048
#define NH 16
#define NKV 4
#define HD 128
#define KV_D 512    // NKV * HD
#define QKV_S 2560  // QKV row stride: Q (2048) + K (512); V goes only to Vt

typedef __attribute__((ext_vector_type(8))) short short8;   // 8 x bf16 (4 VGPRs)
typedef __attribute__((ext_vector_type(4))) float f32x4;    // MFMA accumulator

// fp32 -> bf16 round-to-nearest-even (finite inputs)
__device__ __forceinline__ ushort f2b(float f) {
    unsigned u = __float_as_uint(f);
    return (ushort)((u + 0x7fffu + ((u >> 16) & 1u)) >> 16);
}
__device__ __forceinline__ float b2f(ushort u) {
    return __uint_as_float((unsigned)u << 16);
}

// exp2 via v_exp_f32 (no hidden log2e multiply like __expf)
#if __has_builtin(__builtin_amdgcn_exp2f)
#define EXP2F(x) __builtin_amdgcn_exp2f(x)
#else
#define EXP2F(x) __expf((x) * 0.6931471805599453f)
#endif

#define ASYNC_COPY16(g, l)                                                  \
    __builtin_amdgcn_global_load_lds(                                       \
        (const __attribute__((address_space(1))) void*)(g),                 \
        (__attribute__((address_space(3))) void*)(l), 16, 0, 0)

// ---------------------------------------------------------------------------
// prep_all: one dispatch, 6 independent jobs by bid range:
//   [0,8192)       cast x fp32 -> bf16 (4 elem/thread)
//   [8192,12288)   Wq -> WqkvT rows 0..2047      (transpose+cast)
//   [12288,13312)  Wk -> WqkvT rows 2048..2559
//   [13312,14336)  Wv -> WqkvT rows 2560..3071
//   [14336,18432)  Wo -> WoT
//   [18432,18688)  rope table: tab[t*64+i] = {cos, sin}(t * 10000^(-i/64))
// ---------------------------------------------------------------------------
__global__ __launch_bounds__(256) void prep_all(const float* __restrict__ x,
                                                const float* __restrict__ Wq,
                                                const float* __restrict__ Wk,
                                                const float* __restrict__ Wv,
                                                const float* __restrict__ Wo,
                                                ushort* __restrict__ xb,
                                                ushort* __restrict__ WqkvT,
                                                ushort* __restrict__ WoT,
                                                float2* __restrict__ tab) {
    __shared__ float tile[32][33];
    const int bid = blockIdx.x;
    if (bid < 8192) {                      // cast job
        const int i = bid * 256 + threadIdx.x;
        const float4 v = ((const float4*)x)[i];
        ushort4 u;
        u.x = f2b(v.x); u.y = f2b(v.y); u.z = f2b(v.z); u.w = f2b(v.w);
        ((ushort4*)xb)[i] = u;
        return;
    }
    if (bid >= 18432) {                    // rope table job
        const int idx = (bid - 18432) * 256 + threadIdx.x;
        const int t = idx >> 6, i = idx & 63;
        const float inv = exp2f((float)i * (-13.287712379549449f / 64.0f));
        const float ang = (float)t * inv;
        tab[idx] = make_float2(cosf(ang), sinf(ang));
        return;
    }
    // transpose jobs: W [2048][N] fp32 -> WT [N][2048] bf16
    const float* W;
    ushort* WT;
    int N, rb;
    if (bid < 12288)      { W = Wq; WT = WqkvT;                           N = D_;   rb = bid - 8192; }
    else if (bid < 13312) { W = Wk; WT = WqkvT + (size_t)D_ * D_;         N = KV_D; rb = bid - 12288; }
    else if (bid < 14336) { W = Wv; WT = WqkvT + (size_t)(D_+KV_D) * D_;  N = KV_D; rb = bid - 13312; }
    else                  { W = Wo; WT = WoT;                             N = D_;   rb = bid - 14336; }
    const int bxn = N / 32;
    const int n0 = (rb % bxn) * 32, k0 = (rb / bxn) * 32;
    const int tx = threadIdx.x & 31, ty = threadIdx.x >> 5;  // 32 x 8
    for (int i = ty; i < 32; i += 8)
        tile[i][tx] = W[(size_t)(k0 + i) * N + n0 + tx];
    __syncthreads();
    for (int i = ty; i < 32; i += 8)
        WT[(size_t)(n0 + i) * D_ + k0 + tx] = f2b(tile[tx][i]);
}

// ---------------------------------------------------------------------------
// Fused QKV projection GEMM: C = xb[4096,2048] x WqkvT[3072,2048]^T with a
// per-head epilogue. n-tile (128) == one head:
//   heads 0..15  (Q): rope + 1/sqrt(128)*log2e scale -> QKV cols h*128
//   heads 16..19 (K): rope                           -> QKV cols 2048+(h-16)*128
//   heads 20..23 (V): transpose                      -> Vt [b][kv][d][t]
// K-loop identical to the verified m97 structure (BK=32, global_load_lds
// width-16). Epilogue stages acc as bf16 in LDS (aliased over As/Bs after the
// final barrier), then applies rope from the precomputed table.
// LDS = 34816 B.
// ---------------------------------------------------------------------------
__global__ __launch_bounds__(256) void gemm_qkv(const ushort* __restrict__ A,
                                                const ushort* __restrict__ BT,
                                                ushort* __restrict__ QKV,
                                                ushort* __restrict__ Vt,
                                                const float2* __restrict__ tab) {
    __shared__ ushort smem[128 * 136];     // 34816 B; staging aliases the front
    ushort* As = smem;                     // 128*32 = 4096 ushorts
    ushort* Bs = smem + 4096;
    const int K = D_;
    const int tid = threadIdx.x;
    const int m0 = blockIdx.y * 128, n0 = blockIdx.x * 128;
    const int hid = n0 >> 7;               // 0..23
    const int wave = tid >> 6, lane = tid & 63;
    const int wm = (wave >> 1) * 64, wn = (wave & 1) * 64;
    const int lrow = lane & 15;
    const int quad = lane >> 4;

    f32x4 acc[4][4];
    const f32x4 zero = {0.f, 0.f, 0.f, 0.f};
#pragma unroll
    for (int i = 0; i < 4; ++i)
#pragma unroll
        for (int j = 0; j < 4; ++j) acc[i][j] = zero;

    const int srow = tid >> 2;
    const int scol = (tid & 3) * 8;
    const ushort* Ag = A + (size_t)(m0 + srow) * K + scol;
    const ushort* Bg = BT + (size_t)(n0 + srow) * K + scol;
    ushort* AsT = As + tid * 8;
    ushort* BsT = Bs + tid * 8;

    for (int k0 = 0; k0 < K; k0 += 32) {
        ASYNC_COPY16(Ag + k0, AsT);
        ASYNC_COPY16(Ag + k0 + (size_t)64 * K, AsT + 64 * 32);
        ASYNC_COPY16(Bg + k0, BsT);
        ASYNC_COPY16(Bg + k0 + (size_t)64 * K, BsT + 64 * 32);
        __syncthreads();

        short8 a[4], b[4];
#pragma unroll
        for (int mt = 0; mt < 4; ++mt)
            a[mt] = *(const short8*)&As[(wm + mt * 16 + lrow) * 32 + quad * 8];
#pragma unroll
        for (int nt = 0; nt < 4; ++nt)
            b[nt] = *(const short8*)&Bs[(wn + nt * 16 + lrow) * 32 + quad * 8];
#pragma unroll
        for (int mt = 0; mt < 4; ++mt)
#pragma unroll
            for (int nt = 0; nt < 4; ++nt)
                acc[mt][nt] = __builtin_amdgcn_mfma_f32_16x16x32_bf16(
                    a[mt], b[nt], acc[mt][nt], 0, 0, 0);
        __syncthreads();   // also guarantees staging LDS is dead -> Epi reuse
    }

    // ---- epilogue: acc (C-layout) -> bf16 LDS tile Epi[128 t][136 d-pad] ----
    ushort* Epi = smem;
#pragma unroll
    for (int mt = 0; mt < 4; ++mt)
#pragma unroll
        for (int nt = 0; nt < 4; ++nt)
#pragma unroll
            for (int r = 0; r < 4; ++r)
                Epi[(wm + mt * 16 + quad * 4 + r) * 136 + wn + nt * 16 + lrow] =
                    f2b(acc[mt][nt][r]);
    __syncthreads();

    const int b = m0 >> 10;        // batch (tile rows share one batch)
    const int t0 = m0 & 1023;

    if (hid < NH + NKV) {
        // ---- Q or K head: rope from table, write to QKV ----
        const bool isQ = hid < NH;
        const size_t colbase = isQ ? hid * HD : (size_t)D_ + (hid - NH) * HD;
        // Q scale: 1/sqrt(128) * log2(e) (softmax runs in exp2 domain)
        const float sc = isQ ? (0.08838834764831845f * 1.4426950408889634f) : 1.0f;
        const int r = tid >> 1;            // local t row 0..127
        const int hf = tid & 1;            // d-half group: d in [hf*32, hf*32+32)
        const int t = t0 + r;
        ushort* orow = QKV + (size_t)(m0 + r) * QKV_S + colbase;
        const float4* tab4 = (const float4*)tab;   // 2 (cos,sin) pairs per float4
#pragma unroll
        for (int jj = 0; jj < 4; ++jj) {
            const int dbase = hf * 32 + jj * 8;
            const short8 lo = *(const short8*)&Epi[r * 136 + dbase];
            const short8 hi = *(const short8*)&Epi[r * 136 + 64 + dbase];
            ushort olo[8], ohi[8];
#pragma unroll
            for (int k = 0; k < 4; ++k) {
                const float4 cs = tab4[((t * 64 + dbase) >> 1) + k];
                const float x1a = b2f(lo[2 * k]),     x2a = b2f(hi[2 * k]);
                const float x1b = b2f(lo[2 * k + 1]), x2b = b2f(hi[2 * k + 1]);
                olo[2 * k]     = f2b((x1a * cs.x - x2a * cs.y) * sc);
                ohi[2 * k]     = f2b((x2a * cs.x + x1a * cs.y) * sc);
                olo[2 * k + 1] = f2b((x1b * cs.z - x2b * cs.w) * sc);
                ohi[2 * k + 1] = f2b((x2b * cs.z + x1b * cs.w) * sc);
            }
            *(short8*)&orow[dbase]      = *(short8*)olo;
            *(short8*)&orow[dbase + 64] = *(short8*)ohi;
        }
    } else {
        // ---- V head: transpose Epi[t][d] -> Vt[(b*NKV+kv)*HD + d][t] ----
        const int kv = hid - (NH + NKV);
        const int d = tid & 127;           // conflict-free column reads (2-way)
        const int hf = tid >> 7;           // t-half: [hf*64, hf*64+64)
        ushort* vrow = Vt + ((size_t)((b * NKV + kv) * HD + d)) * T_ + t0 + hf * 64;
#pragma unroll
        for (int jj = 0; jj < 8; ++jj) {
            ushort pk[8];
#pragma unroll
            for (int k = 0; k < 8; ++k)
                pk[k] = Epi[(hf * 64 + jj * 8 + k) * 136 + d];
            *(short8*)&vrow[jj * 8] = *(short8*)pk;
        }
    }
}

// ---------------------------------------------------------------------------
// m97-style bf16 MFMA GEMM (generic, for the output projection):
// C[M,N] fp32 = A[M,K] bf16 x BT[N,K] bf16. (verified rounds 2-6)
// ---------------------------------------------------------------------------
__global__ __launch_bounds__(256) void gemm_bf16(const ushort* __restrict__ A,
                                                 const ushort* __restrict__ BT,
                                                 float* __restrict__ C,
                                                 int M, int N, int K) {
    __shared__ ushort As[128 * 32];
    __shared__ ushort Bs[128 * 32];
    const int tid = threadIdx.x;
    const int m0 = blockIdx.y * 128, n0 = blockIdx.x * 128;
    const int wave = tid >> 6, lane = tid & 63;
    const int wm = (wave >> 1) * 64, wn = (wave & 1) * 64;
    const int lrow = lane & 15;
    const int quad = lane >> 4;

    f32x4 acc[4][4];
    const f32x4 zero = {0.f, 0.f, 0.f, 0.f};
#pragma unroll
    for (int i = 0; i < 4; ++i)
#pragma unroll
        for (int j = 0; j < 4; ++j) acc[i][j] = zero;

    const int srow = tid >> 2;
    const int scol = (tid & 3) * 8;
    const ushort* Ag = A + (size_t)(m0 + srow) * K + scol;
    const ushort* Bg = BT + (size_t)(n0 + srow) * K + scol;
    ushort* AsT = As + tid * 8;
    ushort* BsT = Bs + tid * 8;

    for (int k0 = 0; k0 < K; k0 += 32) {
        ASYNC_COPY16(Ag + k0, AsT);
        ASYNC_COPY16(Ag + k0 + (size_t)64 * K, AsT + 64 * 32);
        ASYNC_COPY16(Bg + k0, BsT);
        ASYNC_COPY16(Bg + k0 + (size_t)64 * K, BsT + 64 * 32);
        __syncthreads();

        short8 a[4], b[4];
#pragma unroll
        for (int mt = 0; mt < 4; ++mt)
            a[mt] = *(const short8*)&As[(wm + mt * 16 + lrow) * 32 + quad * 8];
#pragma unroll
        for (int nt = 0; nt < 4; ++nt)
            b[nt] = *(const short8*)&Bs[(wn + nt * 16 + lrow) * 32 + quad * 8];
#pragma unroll
        for (int mt = 0; mt < 4; ++mt)
#pragma unroll
            for (int nt = 0; nt < 4; ++nt)
                acc[mt][nt] = __builtin_amdgcn_mfma_f32_16x16x32_bf16(
                    a[mt], b[nt], acc[mt][nt], 0, 0, 0);
        __syncthreads();
    }

    const int crow = quad * 4;
    const int ccol = lrow;
#pragma unroll
    for (int mt = 0; mt < 4; ++mt)
#pragma unroll
        for (int nt = 0; nt < 4; ++nt)
#pragma unroll
            for (int r = 0; r < 4; ++r)
                C[(size_t)(m0 + wm + mt * 16 + crow + r) * N +
                  n0 + wn + nt * 16 + ccol] = acc[mt][nt][r];
}

// ---------------------------------------------------------------------------
// MFMA flash attention (round-6 verified): 64 q-rows/WG, 3 WG/CU, heavy-first
// dispatch, exp2-domain softmax. Q/K read from QKV (stride 2560), V from Vt.
// ---------------------------------------------------------------------------
__global__ __launch_bounds__(256) void attn_mfma(const ushort* __restrict__ QKV,
                                                 const ushort* __restrict__ Vt,
                                                 ushort* __restrict__ Yb) {
    __shared__ ushort Ks[64][136];       // [s][d]
    __shared__ ushort Vs[128][72];       // [d][s]
    __shared__ ushort Ps[4][16][72];     // per-wave P tile [qrow][s]

    const int bh = blockIdx.x;
    const int qt = (int)gridDim.y - 1 - (int)blockIdx.y;  // heavy WGs first
    const int b = bh >> 4, h = bh & 15;
    const int kvh = h >> 2;
    const int q0 = qt * 64;
    const int tid = threadIdx.x;
    const int wave = tid >> 6, lane = tid & 63;
    const int ln = lane & 15, quad = lane >> 4;

    // Q fragments (A-layout: m=ln, k=quad*8+j), rows q0 + wave*16 + ln
    short8 qf[4];
    {
        const ushort* qp = QKV + ((size_t)(b * T_ + q0 + wave * 16 + ln)) * QKV_S + h * HD + quad * 8;
#pragma unroll
        for (int f = 0; f < 4; ++f) qf[f] = *(const short8*)(qp + f * 32);
    }

    f32x4 acc[8];
    const f32x4 zero = {0.f, 0.f, 0.f, 0.f};
#pragma unroll
    for (int j = 0; j < 8; ++j) acc[j] = zero;
    float m_r[4], l_r[4];
#pragma unroll
    for (int r = 0; r < 4; ++r) { m_r[r] = -INFINITY; l_r[r] = 0.f; }

    const int qrow = q0 + wave * 16 + quad * 4;   // C-layout row base (+r)

    for (int kt = 0; kt <= qt; ++kt) {
        const int s0 = kt * 64;
        __syncthreads();   // protect previous-iteration Ks/Vs reads
        // stage K tile [64][128] from QKV cols 2048 + kvh*HD (coalesced b128)
#pragma unroll
        for (int c = 0; c < 4; ++c) {
            const int cid = tid + 256 * c;
            const int s = cid >> 4, ch = cid & 15;
            *(short8*)&Ks[s][ch * 8] =
                *(const short8*)&QKV[((size_t)(b * T_ + s0 + s)) * QKV_S + D_ + kvh * HD + ch * 8];
        }
        // stage V^T tile [128][64]
#pragma unroll
        for (int c = 0; c < 4; ++c) {
            const int cid = tid + 256 * c;
            const int d = cid >> 3, ch = cid & 7;
            *(short8*)&Vs[d][ch * 8] =
                *(const short8*)&Vt[((size_t)((b * NKV + kvh) * HD + d)) * T_ + s0 + ch * 8];
        }
        __syncthreads();

        // S = Q K^T : 4 col-tiles of 16
        float sc[4][4];
#pragma unroll
        for (int ct = 0; ct < 4; ++ct) {
            f32x4 s4 = zero;
#pragma unroll
            for (int f = 0; f < 4; ++f)
                s4 = __builtin_amdgcn_mfma_f32_16x16x32_bf16(
                    qf[f], *(const short8*)&Ks[ct * 16 + ln][f * 32 + quad * 8], s4, 0, 0, 0);
#pragma unroll
            for (int r = 0; r < 4; ++r) sc[ct][r] = s4[r];
        }
        // causal mask: only the diagonal tile needs it
        if (kt == qt) {
#pragma unroll
            for (int ct = 0; ct < 4; ++ct)
#pragma unroll
                for (int r = 0; r < 4; ++r)
                    if (s0 + ct * 16 + ln > qrow + r) sc[ct][r] = -INFINITY;
        }
        // online softmax per C-layout row, exp2 domain (log2e folded into Q)
        float alpha[4];
#pragma unroll
        for (int r = 0; r < 4; ++r) {
            float mx = fmaxf(fmaxf(sc[0][r], sc[1][r]), fmaxf(sc[2][r], sc[3][r]));
            mx = fmaxf(mx, __shfl_xor(mx, 1));
            mx = fmaxf(mx, __shfl_xor(mx, 2));
            mx = fmaxf(mx, __shfl_xor(mx, 4));
            mx = fmaxf(mx, __shfl_xor(mx, 8));
            const float mnew = fmaxf(m_r[r], mx);
            alpha[r] = EXP2F(m_r[r] - mnew);
            m_r[r] = mnew;
#pragma unroll
            for (int ct = 0; ct < 4; ++ct) sc[ct][r] = EXP2F(sc[ct][r] - mnew);
            float sum = (sc[0][r] + sc[1][r]) + (sc[2][r] + sc[3][r]);
            sum += __shfl_xor(sum, 1);
            sum += __shfl_xor(sum, 2);
            sum += __shfl_xor(sum, 4);
            sum += __shfl_xor(sum, 8);
            l_r[r] = l_r[r] * alpha[r] + sum;
        }
        // P (C-layout) -> per-wave LDS (wave-private, no barrier needed)
#pragma unroll
        for (int ct = 0; ct < 4; ++ct)
#pragma unroll
            for (int r = 0; r < 4; ++r)
                Ps[wave][quad * 4 + r][ct * 16 + ln] = f2b(sc[ct][r]);
        // rescale O
#pragma unroll
        for (int j = 0; j < 8; ++j)
#pragma unroll
            for (int r = 0; r < 4; ++r) acc[j][r] *= alpha[r];
        // P as A-fragments, two 32-wide k slices
        const short8 pa0 = *(const short8*)&Ps[wave][ln][quad * 8];
        const short8 pa1 = *(const short8*)&Ps[wave][ln][32 + quad * 8];
#pragma unroll
        for (int j = 0; j < 8; ++j) {
            acc[j] = __builtin_amdgcn_mfma_f32_16x16x32_bf16(
                pa0, *(const short8*)&Vs[j * 16 + ln][quad * 8], acc[j], 0, 0, 0);
            acc[j] = __builtin_amdgcn_mfma_f32_16x16x32_bf16(
                pa1, *(const short8*)&Vs[j * 16 + ln][32 + quad * 8], acc[j], 0, 0, 0);
        }
    }

    float invl[4];
#pragma unroll
    for (int r = 0; r < 4; ++r) invl[r] = 1.f / l_r[r];
    ushort* yb = Yb + ((size_t)(b * T_ + qrow)) * D_ + h * HD + ln;
#pragma unroll
    for (int r = 0; r < 4; ++r)
#pragma unroll
        for (int j = 0; j < 8; ++j)
            yb[(size_t)r * D_ + j * 16] = f2b(acc[j][r] * invl[r]);
}

// ---------------------------------------------------------------------------
extern "C" void kernel_launch(void* const* d_in, const int* in_sizes, int n_in,
                              void* d_out, int out_size, void* d_ws, size_t ws_size,
                              hipStream_t stream) {
    const float* x  = (const float*)d_in[0];
    const float* Wq = (const float*)d_in[1];
    const float* Wk = (const float*)d_in[2];
    const float* Wv = (const float*)d_in[3];
    const float* Wo = (const float*)d_in[4];
    float* out = (float*)d_out;

    // Workspace: 80,216,064 B (< round-1's 83,886,080 which is known to fit)
    char* w = (char*)d_ws;
    ushort* xb    = (ushort*)w;  w += (size_t)4096 * D_ * 2;       // 16.78 MB
    ushort* WqkvT = (ushort*)w;  w += (size_t)3072 * D_ * 2;       // 12.58 MB
    ushort* QKV   = (ushort*)w;  w += (size_t)4096 * QKV_S * 2;    // 20.97 MB
    ushort* Vt    = (ushort*)w;  w += (size_t)B_ * KV_D * T_ * 2;  //  4.19 MB
    ushort* Yb    = (ushort*)w;  w += (size_t)4096 * D_ * 2;       // 16.78 MB
    ushort* WoT   = (ushort*)w;  w += (size_t)D_ * D_ * 2;         //  8.39 MB
    float2* tab   = (float2*)w;  w += (size_t)T_ * 64 * 8;         //  0.52 MB

    const int M = B_ * T_;  // 4096
    dim3 blk(256);

    // all input prep (cast, 4 weight transposes, rope table) in one dispatch
    prep_all<<<18688, blk, 0, stream>>>(x, Wq, Wk, Wv, Wo, xb, WqkvT, WoT, tab);

    // fused QKV projection + rope/scale (Q,K) + V transpose epilogue
    gemm_qkv<<<dim3(3072 / 128, M / 128), blk, 0, stream>>>(xb, WqkvT, QKV, Vt, tab);

    attn_mfma<<<dim3(B_ * NH, T_ / 64), blk, 0, stream>>>(QKV, Vt, Yb);

    // output projection: bf16 Y x bf16 Wo^T -> fp32 out
    gemm_bf16<<<dim3(D_ / 128, M / 128), blk, 0, stream>>>(Yb, WoT, out, M, D_, D_);
}